// Round 1
// baseline (103.721 us; speedup 1.0000x reference)
//
#include <hip/hip_runtime.h>
#include <math.h>

#define N 4096
#define D 256
#define HALF 2048
#define MARGIN 0.3f

#define TI 128
#define TJ 128
#define TK 32
#define BJPAD (TJ + 4)

// ---------------------------------------------------------------------------
// Kernel 1: row L2-normalize + init reduction buffers.
// x = v / (||v|| + 1e-6); sq = sum(x*x) = (||v||/(||v||+1e-6))^2
// ---------------------------------------------------------------------------
__global__ __launch_bounds__(256) void k_norm(const float* __restrict__ in,
                                              float* __restrict__ xn,
                                              float* __restrict__ sq,
                                              int* __restrict__ ap,
                                              int* __restrict__ an) {
    const int row = blockIdx.x;
    const int t = threadIdx.x;  // 256 threads, one per column
    float v = in[(size_t)row * D + t];
    float s = v * v;
#pragma unroll
    for (int o = 32; o > 0; o >>= 1) s += __shfl_down(s, o, 64);
    __shared__ float wsum[4];
    __shared__ float inv_s, sq_s;
    if ((t & 63) == 0) wsum[t >> 6] = s;
    __syncthreads();
    if (t == 0) {
        float tot = wsum[0] + wsum[1] + wsum[2] + wsum[3];
        float nrm = sqrtf(tot);
        float inv = 1.0f / (nrm + 1e-6f);
        inv_s = inv;
        float q = nrm * inv;
        sq_s = q * q;
    }
    __syncthreads();
    xn[(size_t)row * D + t] = v * inv_s;
    if (t == 0) {
        sq[row] = sq_s;
        ap[row] = 0;            // bits of 0.0f == pos_any-false fallback
        an[row] = 0x7f800000;   // +inf bits; sentinel for neg_any-false
    }
}

// ---------------------------------------------------------------------------
// Kernel 2: cross-Gram G = X1 (first half) . X2^T (second half), fused with
// masked row/col max-min reduction. dist = sqrt(max(sq_i + sq_j - 2*dot, 1e-6)).
// Row stats -> first-half rows; col stats -> second-half rows (symmetry).
// ---------------------------------------------------------------------------
__global__ __launch_bounds__(256) void k_tile(const float* __restrict__ xn,
                                              const float* __restrict__ sq,
                                              const int* __restrict__ tg,
                                              int* __restrict__ ap,
                                              int* __restrict__ an) {
    __shared__ float As[TI][TK];      // i-major: vector reads along k
    __shared__ float Bsk[TK][BJPAD];  // k-major: vector reads along j
    __shared__ int sra[TI], srn[TI], sca[TJ], scn[TJ];

    const int bi = blockIdx.y, bj = blockIdx.x;
    const int I0 = bi * TI;  // rows in first half
    const int J0 = bj * TJ;  // cols in second half (global row HALF+J0+j)
    const int tid = threadIdx.x;
    const int tx = tid & 15, ty = tid >> 4;

    float acc[8][8];
#pragma unroll
    for (int i = 0; i < 8; ++i)
#pragma unroll
        for (int j = 0; j < 8; ++j) acc[i][j] = 0.f;

    const float* Ag = xn + (size_t)I0 * D;
    const float* Bg = xn + (size_t)(HALF + J0) * D;

    const int f4 = tid & 7;   // float4 slot within a 32-float row
    const int r0 = tid >> 3;  // 0..31

    for (int k0 = 0; k0 < D; k0 += TK) {
        __syncthreads();
#pragma unroll
        for (int rr = 0; rr < 4; ++rr) {
            int r = r0 + rr * 32;
            float4 av = *(const float4*)&Ag[(size_t)r * D + k0 + f4 * 4];
            *(float4*)&As[r][f4 * 4] = av;
            float4 bv = *(const float4*)&Bg[(size_t)r * D + k0 + f4 * 4];
            Bsk[f4 * 4 + 0][r] = bv.x;
            Bsk[f4 * 4 + 1][r] = bv.y;
            Bsk[f4 * 4 + 2][r] = bv.z;
            Bsk[f4 * 4 + 3][r] = bv.w;
        }
        __syncthreads();
#pragma unroll
        for (int kk4 = 0; kk4 < TK / 4; ++kk4) {
            float4 a4[8];
#pragma unroll
            for (int ii = 0; ii < 8; ++ii)
                a4[ii] = *(const float4*)&As[ty * 8 + ii][kk4 * 4];
#pragma unroll
            for (int c = 0; c < 4; ++c) {
                float4 b0 = *(const float4*)&Bsk[kk4 * 4 + c][tx * 8];
                float4 b1 = *(const float4*)&Bsk[kk4 * 4 + c][tx * 8 + 4];
                float bb[8] = {b0.x, b0.y, b0.z, b0.w, b1.x, b1.y, b1.z, b1.w};
#pragma unroll
                for (int ii = 0; ii < 8; ++ii) {
                    float av = (&a4[ii].x)[c];
#pragma unroll
                    for (int jj = 0; jj < 8; ++jj)
                        acc[ii][jj] = fmaf(av, bb[jj], acc[ii][jj]);
                }
            }
        }
    }

    // ---- epilogue: distance + masked max/min --------------------------------
    float sqi[8], sqj[8];
    int tgi[8], tgj[8];
#pragma unroll
    for (int ii = 0; ii < 8; ++ii) {
        sqi[ii] = sq[I0 + ty * 8 + ii];
        tgi[ii] = tg[I0 + ty * 8 + ii];
    }
#pragma unroll
    for (int jj = 0; jj < 8; ++jj) {
        sqj[jj] = sq[HALF + J0 + tx * 8 + jj];
        tgj[jj] = tg[HALF + J0 + tx * 8 + jj];
    }
    const float INF = __int_as_float(0x7f800000);
    float rap[8], ran[8], cap_[8], can_[8];
#pragma unroll
    for (int i = 0; i < 8; ++i) {
        rap[i] = 0.f; ran[i] = INF; cap_[i] = 0.f; can_[i] = INF;
    }
#pragma unroll
    for (int ii = 0; ii < 8; ++ii) {
#pragma unroll
        for (int jj = 0; jj < 8; ++jj) {
            float d2 = sqi[ii] + sqj[jj] - 2.0f * acc[ii][jj];
            float d = sqrtf(fmaxf(d2, 1e-6f));
            if (tgi[ii] == tgj[jj]) {
                rap[ii] = fmaxf(rap[ii], d);
                cap_[jj] = fmaxf(cap_[jj], d);
            } else {
                ran[ii] = fminf(ran[ii], d);
                can_[jj] = fminf(can_[jj], d);
            }
        }
    }

    // block-local reduction in LDS (positive-float bits are int-monotone)
    if (tid < TI) { sra[tid] = 0; srn[tid] = 0x7f800000; }
    if (tid < TJ) { sca[tid] = 0; scn[tid] = 0x7f800000; }
    __syncthreads();
#pragma unroll
    for (int ii = 0; ii < 8; ++ii) {
        atomicMax(&sra[ty * 8 + ii], __float_as_int(rap[ii]));
        atomicMin(&srn[ty * 8 + ii], __float_as_int(ran[ii]));
    }
#pragma unroll
    for (int jj = 0; jj < 8; ++jj) {
        atomicMax(&sca[tx * 8 + jj], __float_as_int(cap_[jj]));
        atomicMin(&scn[tx * 8 + jj], __float_as_int(can_[jj]));
    }
    __syncthreads();
    if (tid < TI) {
        atomicMax(&ap[I0 + tid], sra[tid]);
        atomicMin(&an[I0 + tid], srn[tid]);
    }
    if (tid < TJ) {
        atomicMax(&ap[HALF + J0 + tid], sca[tid]);
        atomicMin(&an[HALF + J0 + tid], scn[tid]);
    }
}

// ---------------------------------------------------------------------------
// Kernel 3: loss = mean(relu(ap - an' + margin)); an' = (an==+inf ? 1 : an)
// ---------------------------------------------------------------------------
__global__ __launch_bounds__(256) void k_loss(const int* __restrict__ ap,
                                              const int* __restrict__ an,
                                              float* __restrict__ out) {
    const int t = threadIdx.x;  // single block of 256
    float s = 0.f;
    for (int i = t; i < N; i += 256) {
        float dap = __int_as_float(ap[i]);
        int anb = an[i];
        float dan = (anb == 0x7f800000) ? 1.0f : __int_as_float(anb);
        float v = dap - dan + MARGIN;
        s += (v > 0.f) ? v : 0.f;
    }
#pragma unroll
    for (int o = 32; o > 0; o >>= 1) s += __shfl_down(s, o, 64);
    __shared__ float wsum[4];
    if ((t & 63) == 0) wsum[t >> 6] = s;
    __syncthreads();
    if (t == 0)
        out[0] = (wsum[0] + wsum[1] + wsum[2] + wsum[3]) / (float)N;
}

extern "C" void kernel_launch(void* const* d_in, const int* in_sizes, int n_in,
                              void* d_out, int out_size, void* d_ws, size_t ws_size,
                              hipStream_t stream) {
    const float* in = (const float*)d_in[0];
    const int* tg = (const int*)d_in[1];
    float* out = (float*)d_out;

    float* xn = (float*)d_ws;                 // N*D floats (4 MB)
    float* sq = xn + (size_t)N * D;           // N floats
    int* ap = (int*)(sq + N);                 // N ints
    int* an = ap + N;                         // N ints

    k_norm<<<N, 256, 0, stream>>>(in, xn, sq, ap, an);
    k_tile<<<dim3(HALF / TJ, HALF / TI), 256, 0, stream>>>(xn, sq, tg, ap, an);
    k_loss<<<1, 256, 0, stream>>>(ap, an, out);
}

// Round 2
// 72.806 us; speedup vs baseline: 1.4246x; 1.4246x over previous
//
#include <hip/hip_runtime.h>
#include <hip/hip_bf16.h>
#include <math.h>

#define N 4096
#define D 256
#define HALF 2048
#define MARGIN 0.3f

#define BM 64        // block tile (rows == cols)
#define BK 32        // k-step == MFMA K
#define LDB 40       // padded LDS row length in bf16 elems (80 B = 20 banks)

typedef __attribute__((ext_vector_type(8))) short bf16x8;  // 8 bf16 = 4 VGPRs
typedef __attribute__((ext_vector_type(4))) float f32x4;   // MFMA C/D

// ---------------------------------------------------------------------------
// Kernel 1: row L2-normalize -> bf16, plus sq (fp32) and ap/an init.
// ---------------------------------------------------------------------------
__global__ __launch_bounds__(256) void k_norm(const float* __restrict__ in,
                                              unsigned short* __restrict__ xnb,
                                              float* __restrict__ sq,
                                              int* __restrict__ ap,
                                              int* __restrict__ an) {
    const int row = blockIdx.x;
    const int t = threadIdx.x;  // one thread per column
    float v = in[(size_t)row * D + t];
    float s = v * v;
#pragma unroll
    for (int o = 32; o > 0; o >>= 1) s += __shfl_down(s, o, 64);
    __shared__ float wsum[4];
    __shared__ float inv_s, sq_s;
    if ((t & 63) == 0) wsum[t >> 6] = s;
    __syncthreads();
    if (t == 0) {
        float tot = wsum[0] + wsum[1] + wsum[2] + wsum[3];
        float nrm = sqrtf(tot);
        float inv = 1.0f / (nrm + 1e-6f);
        inv_s = inv;
        float q = nrm * inv;
        sq_s = q * q;
    }
    __syncthreads();
    float x = v * inv_s;
    // RNE f32 -> bf16
    unsigned int u = __float_as_uint(x);
    xnb[(size_t)row * D + t] =
        (unsigned short)((u + 0x7fffu + ((u >> 16) & 1u)) >> 16);
    if (t == 0) {
        sq[row] = sq_s;
        ap[row] = 0;            // == bits(0.0f), the pos_any-false fallback
        an[row] = 0x7f800000;   // +inf sentinel for neg_any-false
    }
}

// ---------------------------------------------------------------------------
// Kernel 2: bf16-MFMA cross-Gram (first half x second half^T) fused with
// masked row/col max-min. Row stats -> first-half rows, col stats -> second
// half rows (distance symmetry).
// ---------------------------------------------------------------------------
__global__ __launch_bounds__(256) void k_tile(const unsigned short* __restrict__ xnb,
                                              const float* __restrict__ sq,
                                              const int* __restrict__ tg,
                                              int* __restrict__ ap,
                                              int* __restrict__ an) {
    __shared__ unsigned short As[BM * LDB];
    __shared__ unsigned short Bs[BM * LDB];
    __shared__ int sra[BM], srn[BM], sca[BM], scn[BM];

    const int bi = blockIdx.y, bj = blockIdx.x;
    const int I0 = bi * BM;   // first-half rows
    const int J0 = bj * BM;   // second-half rows (= output cols)
    const int tid = threadIdx.x;
    const int wave = tid >> 6, lane = tid & 63;
    const int wm = wave >> 1, wn = wave & 1;   // 2x2 wave grid, 32x32 each
    const int lrow = lane & 15, lquad = lane >> 4;

    f32x4 acc[2][2];
#pragma unroll
    for (int a = 0; a < 2; ++a)
#pragma unroll
        for (int b = 0; b < 2; ++b) acc[a][b] = (f32x4){0.f, 0.f, 0.f, 0.f};

    const unsigned short* Ag = xnb + (size_t)I0 * D;
    const unsigned short* Bg = xnb + (size_t)(HALF + J0) * D;
    const int srow = tid >> 2, sseg = tid & 3;  // 64 rows x 4 x 16B

    for (int k0 = 0; k0 < D; k0 += BK) {
        __syncthreads();
        *(uint4*)&As[srow * LDB + sseg * 8] =
            *(const uint4*)&Ag[(size_t)srow * D + k0 + sseg * 8];
        *(uint4*)&Bs[srow * LDB + sseg * 8] =
            *(const uint4*)&Bg[(size_t)srow * D + k0 + sseg * 8];
        __syncthreads();
        bf16x8 af[2], bfr[2];
#pragma unroll
        for (int mi = 0; mi < 2; ++mi)
            af[mi] = *(const bf16x8*)&As[(wm * 32 + mi * 16 + lrow) * LDB + lquad * 8];
#pragma unroll
        for (int nj = 0; nj < 2; ++nj)
            bfr[nj] = *(const bf16x8*)&Bs[(wn * 32 + nj * 16 + lrow) * LDB + lquad * 8];
#pragma unroll
        for (int mi = 0; mi < 2; ++mi)
#pragma unroll
            for (int nj = 0; nj < 2; ++nj)
                acc[mi][nj] = __builtin_amdgcn_mfma_f32_16x16x32_bf16(
                    af[mi], bfr[nj], acc[mi][nj], 0, 0, 0);
    }

    // ---- epilogue: distances + masked max/min -------------------------------
    // C/D layout: col = lane&15, row = lquad*4 + reg   (per 16x16 tile)
    float sqi[2][4], sqj[2];
    int tgi[2][4], tgj[2];
#pragma unroll
    for (int mi = 0; mi < 2; ++mi)
#pragma unroll
        for (int r = 0; r < 4; ++r) {
            int gi = I0 + wm * 32 + mi * 16 + lquad * 4 + r;
            sqi[mi][r] = sq[gi];
            tgi[mi][r] = tg[gi];
        }
#pragma unroll
    for (int nj = 0; nj < 2; ++nj) {
        int gj = HALF + J0 + wn * 32 + nj * 16 + lrow;
        sqj[nj] = sq[gj];
        tgj[nj] = tg[gj];
    }

    const float INF = __int_as_float(0x7f800000);
    float rap[2][4], ran[2][4], capv[2], canv[2];
#pragma unroll
    for (int mi = 0; mi < 2; ++mi)
#pragma unroll
        for (int r = 0; r < 4; ++r) { rap[mi][r] = 0.f; ran[mi][r] = INF; }
#pragma unroll
    for (int nj = 0; nj < 2; ++nj) { capv[nj] = 0.f; canv[nj] = INF; }

#pragma unroll
    for (int mi = 0; mi < 2; ++mi)
#pragma unroll
        for (int nj = 0; nj < 2; ++nj)
#pragma unroll
            for (int r = 0; r < 4; ++r) {
                float d2 = sqi[mi][r] + sqj[nj] - 2.0f * acc[mi][nj][r];
                float d = sqrtf(fmaxf(d2, 1e-6f));
                if (tgi[mi][r] == tgj[nj]) {
                    rap[mi][r] = fmaxf(rap[mi][r], d);
                    capv[nj] = fmaxf(capv[nj], d);
                } else {
                    ran[mi][r] = fminf(ran[mi][r], d);
                    canv[nj] = fminf(canv[nj], d);
                }
            }

    // shuffle pre-reduce: rows across the 16 lanes sharing lquad
#pragma unroll
    for (int mi = 0; mi < 2; ++mi)
#pragma unroll
        for (int r = 0; r < 4; ++r) {
#pragma unroll
            for (int o = 1; o < 16; o <<= 1) {
                rap[mi][r] = fmaxf(rap[mi][r], __shfl_xor(rap[mi][r], o, 64));
                ran[mi][r] = fminf(ran[mi][r], __shfl_xor(ran[mi][r], o, 64));
            }
        }
    // cols across the 4 quads
#pragma unroll
    for (int nj = 0; nj < 2; ++nj) {
#pragma unroll
        for (int o = 16; o < 64; o <<= 1) {
            capv[nj] = fmaxf(capv[nj], __shfl_xor(capv[nj], o, 64));
            canv[nj] = fminf(canv[nj], __shfl_xor(canv[nj], o, 64));
        }
    }

    if (tid < BM) { sra[tid] = 0; srn[tid] = 0x7f800000;
                    sca[tid] = 0; scn[tid] = 0x7f800000; }
    __syncthreads();
    if (lrow == 0) {  // one lane per (quad, mi, r) row; 2-way contention (wn)
#pragma unroll
        for (int mi = 0; mi < 2; ++mi)
#pragma unroll
            for (int r = 0; r < 4; ++r) {
                int lr = wm * 32 + mi * 16 + lquad * 4 + r;
                atomicMax(&sra[lr], __float_as_int(rap[mi][r]));
                atomicMin(&srn[lr], __float_as_int(ran[mi][r]));
            }
    }
    if (lquad == 0) {  // one lane per col; 2-way contention (wm)
#pragma unroll
        for (int nj = 0; nj < 2; ++nj) {
            int lc = wn * 32 + nj * 16 + lrow;
            atomicMax(&sca[lc], __float_as_int(capv[nj]));
            atomicMin(&scn[lc], __float_as_int(canv[nj]));
        }
    }
    __syncthreads();
    if (tid < BM) {
        atomicMax(&ap[I0 + tid], sra[tid]);
        atomicMin(&an[I0 + tid], srn[tid]);
        atomicMax(&ap[HALF + J0 + tid], sca[tid]);
        atomicMin(&an[HALF + J0 + tid], scn[tid]);
    }
}

// ---------------------------------------------------------------------------
// Kernel 3: loss = mean(relu(ap - an' + margin)); an' = (an==+inf ? 1 : an)
// ---------------------------------------------------------------------------
__global__ __launch_bounds__(1024) void k_loss(const int* __restrict__ ap,
                                               const int* __restrict__ an,
                                               float* __restrict__ out) {
    const int t = threadIdx.x;  // single block of 1024
    float s = 0.f;
#pragma unroll
    for (int i = t; i < N; i += 1024) {
        float dap = __int_as_float(ap[i]);
        int anb = an[i];
        float dan = (anb == 0x7f800000) ? 1.0f : __int_as_float(anb);
        float v = dap - dan + MARGIN;
        s += (v > 0.f) ? v : 0.f;
    }
#pragma unroll
    for (int o = 32; o > 0; o >>= 1) s += __shfl_down(s, o, 64);
    __shared__ float wsum[16];
    if ((t & 63) == 0) wsum[t >> 6] = s;
    __syncthreads();
    if (t == 0) {
        float tot = 0.f;
#pragma unroll
        for (int w = 0; w < 16; ++w) tot += wsum[w];
        out[0] = tot / (float)N;
    }
}

extern "C" void kernel_launch(void* const* d_in, const int* in_sizes, int n_in,
                              void* d_out, int out_size, void* d_ws, size_t ws_size,
                              hipStream_t stream) {
    const float* in = (const float*)d_in[0];
    const int* tg = (const int*)d_in[1];
    float* out = (float*)d_out;

    unsigned short* xnb = (unsigned short*)d_ws;   // N*D bf16 (2 MB)
    float* sq = (float*)(xnb + (size_t)N * D);     // N floats
    int* ap = (int*)(sq + N);                      // N ints
    int* an = ap + N;                              // N ints

    k_norm<<<N, 256, 0, stream>>>(in, xnb, sq, ap, an);
    k_tile<<<dim3(HALF / BM, HALF / BM), 256, 0, stream>>>(xnb, sq, tg, ap, an);
    k_loss<<<1, 1024, 0, stream>>>(ap, an, out);
}